// Round 1
// baseline (691.596 us; speedup 1.0000x reference)
//
#include <hip/hip_runtime.h>
#include <hip/hip_bf16.h>
#include <stdint.h>

#define B_TOT 8192
#define F 64
#define D 256
#define NPAIR 2016
#define PITCH 264  // bf16 elements per LDS row: 256 + 8 pad (16B) to break bank aliasing

typedef __bf16 bf16x8 __attribute__((ext_vector_type(8)));
typedef float f32x4 __attribute__((ext_vector_type(4)));

__device__ __forceinline__ unsigned short f2bf_rne(float f) {
    union { float f; unsigned int u; } x; x.f = f;
    unsigned int u = x.u;
    return (unsigned short)((u + 0x7FFFu + ((u >> 16) & 1u)) >> 16);
}

__global__ __launch_bounds__(256, 4)
void DotInteraction_kernel(const float* __restrict__ X, float* __restrict__ out)
{
    __shared__ unsigned short sX[F * PITCH];  // 64 rows x 264 bf16 = 33792 B

    const int tid = threadIdx.x;
    const int b = blockIdx.x;
    const float* __restrict__ xb = X + (size_t)b * (F * D);

    // ---- Stage: 64x256 fp32 -> bf16 in LDS. 4096 float4 loads, 16/thread, coalesced.
#pragma unroll
    for (int it = 0; it < 16; ++it) {
        const int v   = it * 256 + tid;      // float4 index into the batch
        const int row = v >> 6;              // 4 float4s per... 64 float4s per row
        const int c4  = (v & 63) << 2;       // starting column (float units)
        const float4 f = ((const float4*)xb)[v];
        ushort4 h;
        h.x = f2bf_rne(f.x);
        h.y = f2bf_rne(f.y);
        h.z = f2bf_rne(f.z);
        h.w = f2bf_rne(f.w);
        *(ushort4*)&sX[row * PITCH + c4] = h;   // 8B store, 8B aligned
    }
    __syncthreads();

    const int wave = tid >> 6;
    const int lane = tid & 63;
    const int r16  = lane & 15;
    const int quad = lane >> 4;

    // 10 upper-triangular 16x16 tiles of the 64x64 Gram matrix, round-robin over 4 waves.
    for (int t = wave; t < 10; t += 4) {
        int ti, tj;
        if      (t < 4) { ti = 0; tj = t; }
        else if (t < 7) { ti = 1; tj = t - 3; }
        else if (t < 9) { ti = 2; tj = t - 5; }
        else            { ti = 3; tj = 3; }

        f32x4 acc = {0.f, 0.f, 0.f, 0.f};
        // A operand: A[m][k], m = lane&15 -> row ti*16+m of X, k = quad*8 + j
        // B operand: B[k][n], n = lane&15 -> B[k][n] = X[tj*16+n][k], same row-contiguous read
        const unsigned short* pa = &sX[(ti * 16 + r16) * PITCH + quad * 8];
        const unsigned short* pb = &sX[(tj * 16 + r16) * PITCH + quad * 8];
#pragma unroll
        for (int kk = 0; kk < 8; ++kk) {
            bf16x8 a = *(const bf16x8*)(pa + kk * 32);   // 16B aligned ds_read_b128
            bf16x8 bfr = *(const bf16x8*)(pb + kk * 32);
            acc = __builtin_amdgcn_mfma_f32_16x16x32_bf16(a, bfr, acc, 0, 0, 0);
        }

        // C/D layout: col = lane&15, row = quad*4 + reg   [verified mapping]
        const int j = tj * 16 + r16;
        float* __restrict__ ob = out + (size_t)b * NPAIR;
#pragma unroll
        for (int r = 0; r < 4; ++r) {
            const int i = ti * 16 + quad * 4 + r;
            if (j > i) {
                const int p = (i * (127 - i)) / 2 + (j - i - 1);
                ob[p] = acc[r];
            }
        }
    }
}

extern "C" void kernel_launch(void* const* d_in, const int* in_sizes, int n_in,
                              void* d_out, int out_size, void* d_ws, size_t ws_size,
                              hipStream_t stream) {
    const float* X = (const float*)d_in[0];
    float* out = (float*)d_out;
    DotInteraction_kernel<<<B_TOT, 256, 0, stream>>>(X, out);
}